// Round 1
// baseline (199.831 us; speedup 1.0000x reference)
//
#include <hip/hip_runtime.h>
#include <hip/hip_bf16.h>
#include <hip/hip_fp16.h>
#include <stdint.h>

#define B_SIZE 8192
#define D_SIZE 2048
#define C_SIZE 128
#define N_INNER 255
#define N_LEAF 256
#define NPAD 256
#define NBLK_PATH 512

typedef _Float16 half8 __attribute__((ext_vector_type(8)));
typedef __fp16 pk16x2 __attribute__((ext_vector_type(2)));   // return type of cvt_pkrtz
typedef float f32x4 __attribute__((ext_vector_type(4)));
typedef unsigned short u16;

// ---- fp32 -> (hi,lo) fp16 split, packed pairs ----
__device__ inline uint32_t pkh(float a, float b) {
    pk16x2 h = __builtin_amdgcn_cvt_pkrtz(a, b);
    return __builtin_bit_cast(uint32_t, h);
}
__device__ inline void split4(const float4 v, uint2& hi, uint2& lo) {
    pk16x2 a01 = __builtin_amdgcn_cvt_pkrtz(v.x, v.y);
    pk16x2 a23 = __builtin_amdgcn_cvt_pkrtz(v.z, v.w);
    float r0 = v.x - (float)a01[0];
    float r1 = v.y - (float)a01[1];
    float r2 = v.z - (float)a23[0];
    float r3 = v.w - (float)a23[1];
    hi = make_uint2(__builtin_bit_cast(uint32_t, a01), __builtin_bit_cast(uint32_t, a23));
    lo = make_uint2(pkh(r0, r1), pkh(r2, r3));
}
// 8 consecutive fp32 -> hi/lo half8 fragments, fully in registers
__device__ inline void split8(const float4 v0, const float4 v1, half8& hi8, half8& lo8) {
    pk16x2 a01 = __builtin_amdgcn_cvt_pkrtz(v0.x, v0.y);
    pk16x2 a23 = __builtin_amdgcn_cvt_pkrtz(v0.z, v0.w);
    pk16x2 a45 = __builtin_amdgcn_cvt_pkrtz(v1.x, v1.y);
    pk16x2 a67 = __builtin_amdgcn_cvt_pkrtz(v1.z, v1.w);
    float r0 = v0.x - (float)a01[0];
    float r1 = v0.y - (float)a01[1];
    float r2 = v0.z - (float)a23[0];
    float r3 = v0.w - (float)a23[1];
    float r4 = v1.x - (float)a45[0];
    float r5 = v1.y - (float)a45[1];
    float r6 = v1.z - (float)a67[0];
    float r7 = v1.w - (float)a67[1];
    uint4 h = make_uint4(__builtin_bit_cast(uint32_t, a01), __builtin_bit_cast(uint32_t, a23),
                         __builtin_bit_cast(uint32_t, a45), __builtin_bit_cast(uint32_t, a67));
    uint4 l = make_uint4(pkh(r0, r1), pkh(r2, r3), pkh(r4, r5), pkh(r6, r7));
    hi8 = __builtin_bit_cast(half8, h);
    lo8 = __builtin_bit_cast(half8, l);
}

// ---------------- K-pre (merged): split W -> Wh/Wl  AND  softmax -> Q, logQt ----------------
__global__ __launch_bounds__(256) void prep_kernel(
    const float* __restrict__ Wsrc, u16* __restrict__ Wh, u16* __restrict__ Wl,
    const float* __restrict__ lp, float* __restrict__ Q, float* __restrict__ logQt)
{
    int bid = blockIdx.x;
    int t = threadIdx.x;
    if (bid < 256) {
        // W split: row = bid, each thread 8 k
        int row = bid;
        int k = t * 8;
        uint2 h0, l0, h1, l1;
        if (row < N_INNER) {
            float4 v0 = *(const float4*)(Wsrc + (size_t)row * D_SIZE + k);
            float4 v1 = *(const float4*)(Wsrc + (size_t)row * D_SIZE + k + 4);
            split4(v0, h0, l0); split4(v1, h1, l1);
        } else {
            h0 = l0 = h1 = l1 = make_uint2(0u, 0u);
        }
        *(uint2*)&Wh[(size_t)row * D_SIZE + k]     = h0;
        *(uint2*)&Wh[(size_t)row * D_SIZE + k + 4] = h1;
        *(uint2*)&Wl[(size_t)row * D_SIZE + k]     = l0;
        *(uint2*)&Wl[(size_t)row * D_SIZE + k + 4] = l1;
    } else {
        // softmax over leaf row (bid-256); threads 0..127 work, all hit barriers
        int row = bid - 256;
        __shared__ float red[128];
        float v = 0.f;
        if (t < 128) { v = lp[row * C_SIZE + t]; red[t] = v; }
        __syncthreads();
        for (int s = 64; s > 0; s >>= 1) { if (t < s) red[t] = fmaxf(red[t], red[t + s]); __syncthreads(); }
        float mx = red[0]; __syncthreads();
        float e = 0.f;
        if (t < 128) { e = expf(v - mx); red[t] = e; }
        __syncthreads();
        for (int s = 64; s > 0; s >>= 1) { if (t < s) red[t] += red[t + s]; __syncthreads(); }
        float sum = red[0];
        if (t < 128) {
            Q[row * C_SIZE + t] = e / sum;
            logQt[(size_t)t * N_LEAF + row] = (v - mx) - logf(sum);   // [class][leaf]
        }
    }
}

// ---------------- K1: z_part[kz] = x @ W^T partials, fp16-split MFMA, LDS-FREE ----------------
// BM=64, N=256 (4 waves x 64 cols), BK=32, KSPLIT=4.
// A loaded DIRECTLY from global in MFMA fragment layout (row=mt*16+lr, k=lq*8..+7) and
// split fp32->hi/lo fp16 in registers. The 4 waves read the same A tile -> L1/L2 hits.
// No LDS, no barriers, no lgkm fences: pure dataflow + 1-deep prefetch of A and B.
#define GBM 64
#define GBK 32
#define GKSPLIT 4
#define KCHUNK (D_SIZE / GKSPLIT)   // 512
#define KITERS (KCHUNK / GBK)       // 16

__global__ __launch_bounds__(256, 2) void gemm_mfma(
    const float* __restrict__ x, const u16* __restrict__ Wh, const u16* __restrict__ Wl,
    float* __restrict__ zp)
{
    const int t = threadIdx.x;
    const int lane = t & 63, w = t >> 6;
    const int lr = lane & 15, lq = lane >> 4;
    const int m0 = blockIdx.x * GBM;
    const int kz = blockIdx.z;
    const int kb0 = kz * KCHUNK;

    f32x4 acc[4][4];
    #pragma unroll
    for (int mt = 0; mt < 4; ++mt)
        #pragma unroll
        for (int nt = 0; nt < 4; ++nt) acc[mt][nt] = (f32x4){0.f, 0.f, 0.f, 0.f};

    // per-lane fragment base pointers
    const float* xa = x + (size_t)(m0 + lr) * D_SIZE + kb0 + lq * 8;          // + mt*16 rows
    const u16*   wh = Wh + (size_t)(w * 64 + lr) * D_SIZE + kb0 + lq * 8;     // + nt*16 rows
    const u16*   wl = Wl + (size_t)(w * 64 + lr) * D_SIZE + kb0 + lq * 8;

    // prologue: kt=0 tile into registers
    float4 a0[4], a1[4];
    half8 bh[4], bl[4];
    #pragma unroll
    for (int mt = 0; mt < 4; ++mt) {
        const float* p = xa + (size_t)mt * 16 * D_SIZE;
        a0[mt] = *(const float4*)(p);
        a1[mt] = *(const float4*)(p + 4);
    }
    #pragma unroll
    for (int nt = 0; nt < 4; ++nt) {
        bh[nt] = *(const half8*)(wh + (size_t)nt * 16 * D_SIZE);
        bl[nt] = *(const half8*)(wl + (size_t)nt * 16 * D_SIZE);
    }

    #pragma unroll
    for (int kt = 0; kt < KITERS; ++kt) {
        // 1. issue next-tile loads first (latency hides under converts + MFMAs)
        float4 na0[4], na1[4];
        half8 nbh[4], nbl[4];
        if (kt + 1 < KITERS) {
            const int ko = (kt + 1) * GBK;
            #pragma unroll
            for (int mt = 0; mt < 4; ++mt) {
                const float* p = xa + (size_t)mt * 16 * D_SIZE + ko;
                na0[mt] = *(const float4*)(p);
                na1[mt] = *(const float4*)(p + 4);
            }
            #pragma unroll
            for (int nt = 0; nt < 4; ++nt) {
                nbh[nt] = *(const half8*)(wh + (size_t)nt * 16 * D_SIZE + ko);
                nbl[nt] = *(const half8*)(wl + (size_t)nt * 16 * D_SIZE + ko);
            }
        }
        // 2. convert current A in registers
        half8 ah[4], al[4];
        #pragma unroll
        for (int mt = 0; mt < 4; ++mt) split8(a0[mt], a1[mt], ah[mt], al[mt]);
        // 3. MFMA (hi*hi + hi*lo + lo*hi)
        #pragma unroll
        for (int mt = 0; mt < 4; ++mt)
            #pragma unroll
            for (int nt = 0; nt < 4; ++nt) {
                acc[mt][nt] = __builtin_amdgcn_mfma_f32_16x16x32_f16(ah[mt], bh[nt], acc[mt][nt], 0, 0, 0);
                acc[mt][nt] = __builtin_amdgcn_mfma_f32_16x16x32_f16(ah[mt], bl[nt], acc[mt][nt], 0, 0, 0);
                acc[mt][nt] = __builtin_amdgcn_mfma_f32_16x16x32_f16(al[mt], bh[nt], acc[mt][nt], 0, 0, 0);
            }
        // 4. advance
        if (kt + 1 < KITERS) {
            #pragma unroll
            for (int mt = 0; mt < 4; ++mt) { a0[mt] = na0[mt]; a1[mt] = na1[mt]; }
            #pragma unroll
            for (int nt = 0; nt < 4; ++nt) { bh[nt] = nbh[nt]; bl[nt] = nbl[nt]; }
        }
    }

    float* zout = zp + (size_t)kz * B_SIZE * NPAD;
    #pragma unroll
    for (int mt = 0; mt < 4; ++mt) {
        #pragma unroll
        for (int nt = 0; nt < 4; ++nt) {
            int gn = w * 64 + nt * 16 + lr;
            #pragma unroll
            for (int r = 0; r < 4; ++r) {
                int gm = m0 + mt * 16 + lq * 4 + r;
                zout[(size_t)gm * NPAD + gn] = acc[mt][nt][r];
            }
        }
    }
}

// ---------------- K2: fused reduce + sigmoid + paths + penalties + loss + argmax gather ----------------
// 512 blocks x 4 waves x 4 rows. pbuf wave-private -> no per-iter barriers (lgkm fence only).
// One real __syncthreads after LDS-accumulator init, one before the partial write-out.
__global__ __launch_bounds__(256) void path_kernel(
    const float* __restrict__ z, const int* __restrict__ target,
    const float* __restrict__ bvec, const float* __restrict__ beta,
    const float* __restrict__ Q, const float* __restrict__ logQt,
    float* __restrict__ partial, float* __restrict__ out)
{
    __shared__ float pbuf[4][256];
    __shared__ float s_num[128], s_den[128], s_loss;
    const int t = threadIdx.x, w = t >> 6, lane = t & 63;
    const int c0 = lane * 4;
    float pnum[4] = {0.f, 0.f, 0.f, 0.f};
    float pden[4] = {0.f, 0.f, 0.f, 0.f};
    float loss = 0.f;

    if (t < 128) s_num[t] = 0.f;
    else s_den[t - 128] = 0.f;
    if (t == 0) s_loss = 0.f;
    __syncthreads();   // init visible to all waves before end-of-kernel atomics

    float bet[4], bia[4];
    #pragma unroll
    for (int j = 0; j < 4; ++j) {
        int c = c0 + j;
        bet[j] = (c < N_INNER) ? beta[c] : 0.f;
        bia[j] = (c < N_INNER) ? bvec[c] : 0.f;
    }

    for (int i = 0; i < 4; ++i) {
        int r = blockIdx.x * 16 + w * 4 + i;
        float4 s = make_float4(0.f, 0.f, 0.f, 0.f);
        #pragma unroll
        for (int p = 0; p < GKSPLIT; ++p) {
            float4 v = *(const float4*)(z + ((size_t)p * B_SIZE + r) * NPAD + c0);
            s.x += v.x; s.y += v.y; s.z += v.z; s.w += v.w;
        }
        float zv[4] = {s.x, s.y, s.z, s.w};
        float pv[4];
        #pragma unroll
        for (int j = 0; j < 4; ++j) {
            int c = c0 + j;
            pv[j] = (c < N_INNER) ? 1.f / (1.f + expf(-bet[j] * (zv[j] + bia[j]))) : 0.f;
        }
        *(float4*)&pbuf[w][c0] = make_float4(pv[0], pv[1], pv[2], pv[3]);
        asm volatile("s_waitcnt lgkmcnt(0)" ::: "memory");  // wave-private LDS visibility

        int tg = target[r];
        float4 lq4 = *(const float4*)(logQt + (size_t)tg * N_LEAF + c0);
        float lqa[4] = {lq4.x, lq4.y, lq4.z, lq4.w};
        float lsum = 0.f, bestV = -1.f;
        int bestI = 0;
        #pragma unroll
        for (int j = 0; j < 4; ++j) {
            int leaf = c0 + j;
            float pl = 1.f;
            #pragma unroll
            for (int d = 0; d < 8; ++d) {
                int node = (1 << d) - 1 + (leaf >> (8 - d));
                int bit = (leaf >> (7 - d)) & 1;
                float pvn = pbuf[w][node];
                pl *= bit ? pvn : (1.f - pvn);
            }
            lsum += pl * lqa[j];
            if (pl > bestV) { bestV = pl; bestI = leaf; }  // ascending j keeps lowest tie
        }
        if (lane < 32) {
            #pragma unroll
            for (int j = 0; j < 4; ++j) {
                int c = c0 + j;
                if (c < 127) {
                    int h = c + 1; int d = 31 - __clz(h);
                    float pp = 1.f;
                    for (int e = 0; e < d; ++e) {
                        int ha = h >> (d - e);
                        int bit = (h >> (d - 1 - e)) & 1;
                        float pvn = pbuf[w][ha - 1];
                        pp *= bit ? pvn : (1.f - pvn);
                    }
                    pnum[j] += pbuf[w][c] * pp;
                    pden[j] += pp;
                }
            }
        }
        #pragma unroll
        for (int m = 1; m < 64; m <<= 1) {
            lsum += __shfl_xor(lsum, m, 64);
            float ov = __shfl_xor(bestV, m, 64);
            int   oi = __shfl_xor(bestI, m, 64);
            if (ov > bestV || (ov == bestV && oi < bestI)) { bestV = ov; bestI = oi; }
        }
        loss += lsum;
        out[1 + (size_t)r * C_SIZE + lane]      = Q[bestI * C_SIZE + lane];
        out[1 + (size_t)r * C_SIZE + lane + 64] = Q[bestI * C_SIZE + lane + 64];
        asm volatile("" ::: "memory");  // keep next iter's pbuf write after this iter's reads
    }

    // block-level reduction via LDS atomics, then one global store per thread
    if (lane < 32) {
        #pragma unroll
        for (int j = 0; j < 4; ++j) {
            int c = c0 + j;
            if (c < 127) {
                atomicAdd(&s_num[c], pnum[j]);
                atomicAdd(&s_den[c], pden[j]);
            }
        }
    }
    if (lane == 0) atomicAdd(&s_loss, loss);
    __syncthreads();
    float* rec = partial + (size_t)blockIdx.x * 256;
    if (t < 127)        rec[t] = s_num[t];
    else if (t == 127)  rec[127] = s_loss;
    else if (t < 255)   rec[t] = s_den[t - 128];
    else                rec[255] = 0.f;
}

// ---------------- K3: reduce partials + finalize total ----------------
__global__ __launch_bounds__(256) void reduce_kernel(
    const float* __restrict__ partial, float* __restrict__ out)
{
    __shared__ float s[256];
    __shared__ float red[128];
    int t = threadIdx.x;
    float a0 = 0.f, a1 = 0.f, a2 = 0.f, a3 = 0.f;
    for (int r = 0; r < NBLK_PATH; r += 4) {
        a0 += partial[(size_t)(r + 0) * 256 + t];
        a1 += partial[(size_t)(r + 1) * 256 + t];
        a2 += partial[(size_t)(r + 2) * 256 + t];
        a3 += partial[(size_t)(r + 3) * 256 + t];
    }
    s[t] = (a0 + a1) + (a2 + a3);
    __syncthreads();
    float term = 0.f;
    if (t < 127) {
        int d = 31 - __clz(t + 1);
        float lam = 0.1f * exp2f(-(float)(d + 1));
        float pen = s[t] / s[128 + t];
        term = lam * 0.5f * (logf(pen) + logf(1.f - pen));
    }
    if (t < 128) { red[t] = term; }
    __syncthreads();
    for (int sh = 64; sh > 0; sh >>= 1) { if (t < sh) red[t] += red[t + sh]; __syncthreads(); }
    if (t == 0) out[0] = -(s[127] / (float)B_SIZE) - red[0];
}

extern "C" void kernel_launch(void* const* d_in, const int* in_sizes, int n_in,
                              void* d_out, int out_size, void* d_ws, size_t ws_size,
                              hipStream_t stream)
{
    const float* x    = (const float*)d_in[0];
    const int*   tgt  = (const int*)d_in[1];
    const float* W    = (const float*)d_in[2];
    const float* b    = (const float*)d_in[3];
    const float* beta = (const float*)d_in[4];
    const float* lp   = (const float*)d_in[5];
    float* out = (float*)d_out;

    // ws layout (floats): z partials (4 x 8192 x 256), Q (256x128), logQt (128x256),
    // Wh/Wl (u16 256x2048 each), block partials (512 x 256)
    float* z     = (float*)d_ws;
    float* Q     = z + (size_t)GKSPLIT * B_SIZE * NPAD;
    float* logQt = Q + (size_t)N_LEAF * C_SIZE;
    u16*   Wh    = (u16*)(logQt + (size_t)C_SIZE * N_LEAF);
    u16*   Wl    = Wh + (size_t)N_LEAF * D_SIZE;
    float* partial = (float*)(Wl + (size_t)N_LEAF * D_SIZE);

    prep_kernel<<<512, 256, 0, stream>>>(W, Wh, Wl, lp, Q, logQt);

    dim3 ggrid(B_SIZE / GBM, 1, GKSPLIT);   // 128 x 1 x 4 = 512 blocks
    gemm_mfma<<<ggrid, 256, 0, stream>>>(x, Wh, Wl, z);

    path_kernel<<<NBLK_PATH, 256, 0, stream>>>(
        z, tgt, b, beta, Q, logQt, partial, out);

    reduce_kernel<<<1, 256, 0, stream>>>(partial, out);
}